// Round 1
// baseline (239.885 us; speedup 1.0000x reference)
//
#include <hip/hip_runtime.h>
#include <stdint.h>

// Problem constants (B,T,D)=(32,512,512), M=4096, N_FALSE_NEG=64, TEMP=0.1
#define T_DIM 512
#define D_DIM 512
#define M_ROWS 4096
#define NNEG 64
#define INV_TEMP 10.0f
#define SPAN 4094u        // maxval - minval = (M-2) - 0
#define MULT 1024u        // (2^16 % 4094)^2 % 4094

struct U2 { uint32_t a, b; };

__host__ __device__ constexpr uint32_t rotl32(uint32_t x, uint32_t r) {
  return (x << r) | (x >> (32u - r));
}

// JAX threefry2x32 (20 rounds, key-injection schedule per jax/_src/prng.py)
__host__ __device__ constexpr U2 tf2x32(uint32_t k0, uint32_t k1,
                                        uint32_t c0, uint32_t c1) {
  uint32_t ks0 = k0, ks1 = k1, ks2 = k0 ^ k1 ^ 0x1BD11BDAu;
  uint32_t x0 = c0 + ks0, x1 = c1 + ks1;
  // group 0: rot {13,15,26,6}
  x0 += x1; x1 = rotl32(x1, 13); x1 ^= x0;
  x0 += x1; x1 = rotl32(x1, 15); x1 ^= x0;
  x0 += x1; x1 = rotl32(x1, 26); x1 ^= x0;
  x0 += x1; x1 = rotl32(x1, 6);  x1 ^= x0;
  x0 += ks1; x1 += ks2 + 1u;
  // group 1: rot {17,29,16,24}
  x0 += x1; x1 = rotl32(x1, 17); x1 ^= x0;
  x0 += x1; x1 = rotl32(x1, 29); x1 ^= x0;
  x0 += x1; x1 = rotl32(x1, 16); x1 ^= x0;
  x0 += x1; x1 = rotl32(x1, 24); x1 ^= x0;
  x0 += ks2; x1 += ks0 + 2u;
  // group 2
  x0 += x1; x1 = rotl32(x1, 13); x1 ^= x0;
  x0 += x1; x1 = rotl32(x1, 15); x1 ^= x0;
  x0 += x1; x1 = rotl32(x1, 26); x1 ^= x0;
  x0 += x1; x1 = rotl32(x1, 6);  x1 ^= x0;
  x0 += ks0; x1 += ks1 + 3u;
  // group 3
  x0 += x1; x1 = rotl32(x1, 17); x1 ^= x0;
  x0 += x1; x1 = rotl32(x1, 29); x1 ^= x0;
  x0 += x1; x1 = rotl32(x1, 16); x1 ^= x0;
  x0 += x1; x1 = rotl32(x1, 24); x1 ^= x0;
  x0 += ks1; x1 += ks2 + 4u;
  // group 4
  x0 += x1; x1 = rotl32(x1, 13); x1 ^= x0;
  x0 += x1; x1 = rotl32(x1, 15); x1 ^= x0;
  x0 += x1; x1 = rotl32(x1, 26); x1 ^= x0;
  x0 += x1; x1 = rotl32(x1, 6);  x1 ^= x0;
  x0 += ks2; x1 += ks0 + 5u;
  return U2{x0, x1};
}

// jax.random.key(42) = (0,42); partitionable split(key,2): k_i = tf(key,(0,i))
constexpr U2 KHI = tf2x32(0u, 42u, 0u, 0u);  // k1 -> higher_bits
constexpr U2 KLO = tf2x32(0u, 42u, 0u, 1u);  // k2 -> lower_bits

// sel[m][j] per jax.random.randint + the (r >= i) false-negative shift
__device__ inline uint32_t sel_index(uint32_t m, uint32_t j) {
  uint32_t pos = m * 64u + j;  // row-major flat index into (M, NNEG)
  U2 h = tf2x32(KHI.a, KHI.b, 0u, pos);
  U2 l = tf2x32(KLO.a, KLO.b, 0u, pos);
  uint32_t hi = h.a ^ h.b;     // partitionable 32-bit random_bits = o1^o2
  uint32_t lo = l.a ^ l.b;
  uint32_t r = ((hi % SPAN) * MULT + (lo % SPAN)) % SPAN;
  return r + (r >= m ? 1u : 0u);
}

// Kernel 1: per-row gather + fused norm sums + sim0; 128 thr = 2 waves, float4/lane
__global__ __launch_bounds__(128) void k_gather_norm(
    const float* __restrict__ pred, const float* __restrict__ enc,
    const int* __restrict__ ids, float* __restrict__ nenc,
    float* __restrict__ npred, float* __restrict__ sim0, float* accum) {
  int m = blockIdx.x;
  int tid = threadIdx.x;
  if (m == 0 && tid < 2) accum[tid] = 0.0f;

  int row = ids[2 * m];
  int col = ids[2 * m + 1];
  size_t base = ((size_t)row * T_DIM + col) * D_DIM;  // 2KB-aligned

  float4 e = ((const float4*)(enc + base))[tid];
  float4 p = ((const float4*)(pred + base))[tid];

  float se = e.x * e.x + e.y * e.y + e.z * e.z + e.w * e.w;
  float sp = p.x * p.x + p.y * p.y + p.z * p.z + p.w * p.w;
  float dp = e.x * p.x + e.y * p.y + e.z * p.z + e.w * p.w;

  #pragma unroll
  for (int off = 1; off < 64; off <<= 1) {
    se += __shfl_xor(se, off, 64);
    sp += __shfl_xor(sp, off, 64);
    dp += __shfl_xor(dp, off, 64);
  }
  __shared__ float red[2][3];
  int w = tid >> 6;
  if ((tid & 63) == 0) { red[w][0] = se; red[w][1] = sp; red[w][2] = dp; }
  __syncthreads();
  se = red[0][0] + red[1][0];
  sp = red[0][1] + red[1][1];
  dp = red[0][2] + red[1][2];

  float inv_e = 1.0f / fmaxf(sqrtf(se), 1e-12f);
  float inv_p = 1.0f / fmaxf(sqrtf(sp), 1e-12f);

  float4 en = make_float4(e.x * inv_e, e.y * inv_e, e.z * inv_e, e.w * inv_e);
  float4 pn = make_float4(p.x * inv_p, p.y * inv_p, p.z * inv_p, p.w * inv_p);
  ((float4*)(nenc + (size_t)m * D_DIM))[tid] = en;
  ((float4*)(npred + (size_t)m * D_DIM))[tid] = pn;
  if (tid == 0) sim0[m] = dp * inv_e * inv_p * INV_TEMP;
}

// Kernel 2: one wave per row; 64 negative dots + online LSE
__global__ __launch_bounds__(256) void k_contrast(
    const float* __restrict__ nenc, const float* __restrict__ npred,
    const float* __restrict__ sim0arr, float* accum) {
  int lane = threadIdx.x & 63;
  int wave = threadIdx.x >> 6;
  int m = blockIdx.x * 4 + wave;

  const float4* pr = (const float4*)(npred + (size_t)m * D_DIM);
  float4 p0 = pr[lane];        // elems [4*lane, 4*lane+4)
  float4 p1 = pr[lane + 64];   // elems [256+4*lane, ...)

  uint32_t selreg = sel_index((uint32_t)m, (uint32_t)lane);

  float s0 = sim0arr[m];
  float maxv = s0, sumexp = 1.0f, maxneg = -1e30f;

  for (int j = 0; j < NNEG; ++j) {
    int sel = __shfl((int)selreg, j, 64);
    const float4* er = (const float4*)(nenc + (size_t)sel * D_DIM);
    float4 e0 = er[lane];
    float4 e1 = er[lane + 64];
    float d = p0.x * e0.x + p0.y * e0.y + p0.z * e0.z + p0.w * e0.w
            + p1.x * e1.x + p1.y * e1.y + p1.z * e1.z + p1.w * e1.w;
    #pragma unroll
    for (int off = 1; off < 64; off <<= 1) d += __shfl_xor(d, off, 64);
    float sim = d * INV_TEMP;
    maxneg = fmaxf(maxneg, sim);
    if (sim > maxv) {            // wave-uniform branch (d identical on all lanes)
      sumexp = sumexp * expf(maxv - sim) + 1.0f;
      maxv = sim;
    } else {
      sumexp += expf(sim - maxv);
    }
  }
  if (lane == 0) {
    float lse = maxv + logf(sumexp);
    atomicAdd(&accum[0], lse - s0);
    atomicAdd(&accum[1], (s0 >= maxneg) ? 1.0f : 0.0f);
  }
}

__global__ void k_finalize(const float* accum, float* out) {
  out[0] = accum[0] * (1.0f / M_ROWS);
  out[1] = accum[1] * (1.0f / M_ROWS);
}

extern "C" void kernel_launch(void* const* d_in, const int* in_sizes, int n_in,
                              void* d_out, int out_size, void* d_ws, size_t ws_size,
                              hipStream_t stream) {
  const float* pred = (const float*)d_in[0];
  const float* enc  = (const float*)d_in[1];
  const int*   ids  = (const int*)d_in[2];
  float* out = (float*)d_out;

  // workspace layout (fp32): nenc[M*D] | npred[M*D] | sim0[M] | accum[2]
  float* nenc  = (float*)d_ws;
  float* npred = nenc + (size_t)M_ROWS * D_DIM;
  float* sim0  = npred + (size_t)M_ROWS * D_DIM;
  float* accum = sim0 + M_ROWS;

  k_gather_norm<<<M_ROWS, 128, 0, stream>>>(pred, enc, ids, nenc, npred, sim0, accum);
  k_contrast<<<M_ROWS / 4, 256, 0, stream>>>(nenc, npred, sim0, accum);
  k_finalize<<<1, 1, 0, stream>>>(accum, out);
}

// Round 2
// 118.526 us; speedup vs baseline: 2.0239x; 2.0239x over previous
//
#include <hip/hip_runtime.h>
#include <stdint.h>

// (B,T,D)=(32,512,512), M=4096, N_FALSE_NEG=64, TEMP=0.1
#define T_DIM 512
#define D_DIM 512
#define M_ROWS 4096
#define NNEG 64
#define INV_TEMP 10.0f
#define SPAN 4094u        // maxval - minval = (M-2) - 0
#define MULT 1024u        // (2^16 % 4094)^2 % 4094

struct U2 { uint32_t a, b; };

__host__ __device__ constexpr uint32_t rotl32(uint32_t x, uint32_t r) {
  return (x << r) | (x >> (32u - r));
}

// JAX threefry2x32 (20 rounds) — verified bit-exact in round 1 (absmax 0.0)
__host__ __device__ constexpr U2 tf2x32(uint32_t k0, uint32_t k1,
                                        uint32_t c0, uint32_t c1) {
  uint32_t ks0 = k0, ks1 = k1, ks2 = k0 ^ k1 ^ 0x1BD11BDAu;
  uint32_t x0 = c0 + ks0, x1 = c1 + ks1;
  x0 += x1; x1 = rotl32(x1, 13); x1 ^= x0;
  x0 += x1; x1 = rotl32(x1, 15); x1 ^= x0;
  x0 += x1; x1 = rotl32(x1, 26); x1 ^= x0;
  x0 += x1; x1 = rotl32(x1, 6);  x1 ^= x0;
  x0 += ks1; x1 += ks2 + 1u;
  x0 += x1; x1 = rotl32(x1, 17); x1 ^= x0;
  x0 += x1; x1 = rotl32(x1, 29); x1 ^= x0;
  x0 += x1; x1 = rotl32(x1, 16); x1 ^= x0;
  x0 += x1; x1 = rotl32(x1, 24); x1 ^= x0;
  x0 += ks2; x1 += ks0 + 2u;
  x0 += x1; x1 = rotl32(x1, 13); x1 ^= x0;
  x0 += x1; x1 = rotl32(x1, 15); x1 ^= x0;
  x0 += x1; x1 = rotl32(x1, 26); x1 ^= x0;
  x0 += x1; x1 = rotl32(x1, 6);  x1 ^= x0;
  x0 += ks0; x1 += ks1 + 3u;
  x0 += x1; x1 = rotl32(x1, 17); x1 ^= x0;
  x0 += x1; x1 = rotl32(x1, 29); x1 ^= x0;
  x0 += x1; x1 = rotl32(x1, 16); x1 ^= x0;
  x0 += x1; x1 = rotl32(x1, 24); x1 ^= x0;
  x0 += ks1; x1 += ks2 + 4u;
  x0 += x1; x1 = rotl32(x1, 13); x1 ^= x0;
  x0 += x1; x1 = rotl32(x1, 15); x1 ^= x0;
  x0 += x1; x1 = rotl32(x1, 26); x1 ^= x0;
  x0 += x1; x1 = rotl32(x1, 6);  x1 ^= x0;
  x0 += ks2; x1 += ks0 + 5u;
  return U2{x0, x1};
}

constexpr U2 KHI = tf2x32(0u, 42u, 0u, 0u);  // split(key(42))[0]
constexpr U2 KLO = tf2x32(0u, 42u, 0u, 1u);  // split(key(42))[1]

__device__ inline uint32_t sel_index(uint32_t m, uint32_t j) {
  uint32_t pos = m * 64u + j;
  U2 h = tf2x32(KHI.a, KHI.b, 0u, pos);
  U2 l = tf2x32(KLO.a, KLO.b, 0u, pos);
  uint32_t hi = h.a ^ h.b;
  uint32_t lo = l.a ^ l.b;
  uint32_t r = ((hi % SPAN) * MULT + (lo % SPAN)) % SPAN;
  return r + (r >= m ? 1u : 0u);
}

// --- bf16 pack/unpack helpers ---
__device__ inline uint32_t pack_bf2(float lo, float hi) {  // RNE round both
  uint32_t ul = __float_as_uint(lo); ul += 0x7fffu + ((ul >> 16) & 1u);
  uint32_t uh = __float_as_uint(hi); uh += 0x7fffu + ((uh >> 16) & 1u);
  return (ul >> 16) | (uh & 0xffff0000u);
}
__device__ inline float bflo(int v) { return __uint_as_float(((uint32_t)v) << 16); }
__device__ inline float bfhi(int v) { return __uint_as_float(((uint32_t)v) & 0xffff0000u); }

// Kernel 1: 1 wave per row (4 rows/block). Gather, fused norm sums, sim0,
// write normalized rows as bf16 (lane holds elems [8*lane, 8*lane+8)).
__global__ __launch_bounds__(256) void k_gather_norm(
    const float* __restrict__ pred, const float* __restrict__ enc,
    const int* __restrict__ ids, int4* __restrict__ nenc,
    int4* __restrict__ npred, float* __restrict__ sim0) {
  int lane = threadIdx.x & 63;
  int wave = threadIdx.x >> 6;
  int m = blockIdx.x * 4 + wave;

  int2 rc = ((const int2*)ids)[m];
  size_t base = ((size_t)rc.x * T_DIM + rc.y) * D_DIM;
  const float4* ep = (const float4*)(enc + base);
  const float4* pp = (const float4*)(pred + base);
  float4 e0 = ep[2 * lane], e1 = ep[2 * lane + 1];
  float4 p0 = pp[2 * lane], p1 = pp[2 * lane + 1];

  float se = e0.x*e0.x + e0.y*e0.y + e0.z*e0.z + e0.w*e0.w
           + e1.x*e1.x + e1.y*e1.y + e1.z*e1.z + e1.w*e1.w;
  float sp = p0.x*p0.x + p0.y*p0.y + p0.z*p0.z + p0.w*p0.w
           + p1.x*p1.x + p1.y*p1.y + p1.z*p1.z + p1.w*p1.w;
  float dp = e0.x*p0.x + e0.y*p0.y + e0.z*p0.z + e0.w*p0.w
           + e1.x*p1.x + e1.y*p1.y + e1.z*p1.z + e1.w*p1.w;

  #pragma unroll
  for (int off = 1; off < 64; off <<= 1) {
    se += __shfl_xor(se, off, 64);
    sp += __shfl_xor(sp, off, 64);
    dp += __shfl_xor(dp, off, 64);
  }

  float inv_e = 1.0f / fmaxf(sqrtf(se), 1e-12f);
  float inv_p = 1.0f / fmaxf(sqrtf(sp), 1e-12f);

  int4 eq, pq;
  eq.x = pack_bf2(e0.x * inv_e, e0.y * inv_e);
  eq.y = pack_bf2(e0.z * inv_e, e0.w * inv_e);
  eq.z = pack_bf2(e1.x * inv_e, e1.y * inv_e);
  eq.w = pack_bf2(e1.z * inv_e, e1.w * inv_e);
  pq.x = pack_bf2(p0.x * inv_p, p0.y * inv_p);
  pq.y = pack_bf2(p0.z * inv_p, p0.w * inv_p);
  pq.z = pack_bf2(p1.x * inv_p, p1.y * inv_p);
  pq.w = pack_bf2(p1.z * inv_p, p1.w * inv_p);
  nenc[m * 64 + lane] = eq;
  npred[m * 64 + lane] = pq;
  if (lane == 0) sim0[m] = dp * inv_e * inv_p * INV_TEMP;
}

// Kernel 2: 1 wave per row; j unrolled x4; no online max (|sim|<=10 so
// exp(sim) is fp32-safe unshifted); block partials, no atomics.
__global__ __launch_bounds__(256) void k_contrast(
    const int4* __restrict__ nenc, const int4* __restrict__ npred,
    const float* __restrict__ sim0arr, float2* __restrict__ partials) {
  int lane = threadIdx.x & 63;
  int wave = threadIdx.x >> 6;
  int m = blockIdx.x * 4 + wave;

  __shared__ int sel_lds[4][64];
  __shared__ float2 wred[4];
  sel_lds[wave][lane] = (int)sel_index((uint32_t)m, (uint32_t)lane);

  int4 pq = npred[m * 64 + lane];
  float p0 = bflo(pq.x), p1 = bfhi(pq.x), p2 = bflo(pq.y), p3 = bfhi(pq.y);
  float p4 = bflo(pq.z), p5 = bfhi(pq.z), p6 = bflo(pq.w), p7 = bfhi(pq.w);

  float s0 = sim0arr[m];
  float sumexp = __expf(s0);
  float maxneg = -1e30f;

  for (int jj = 0; jj < NNEG; jj += 4) {
    int4 s4 = *((const int4*)&sel_lds[wave][jj]);  // wave-uniform broadcast
    float d[4];
    #pragma unroll
    for (int u = 0; u < 4; ++u) {
      int sel = (u == 0) ? s4.x : (u == 1) ? s4.y : (u == 2) ? s4.z : s4.w;
      int4 q = nenc[(size_t)sel * 64 + lane];
      float a = p0 * bflo(q.x);
      a = fmaf(p1, bfhi(q.x), a);
      a = fmaf(p2, bflo(q.y), a);
      a = fmaf(p3, bfhi(q.y), a);
      a = fmaf(p4, bflo(q.z), a);
      a = fmaf(p5, bfhi(q.z), a);
      a = fmaf(p6, bflo(q.w), a);
      a = fmaf(p7, bfhi(q.w), a);
      d[u] = a;
    }
    #pragma unroll
    for (int off = 1; off < 64; off <<= 1) {  // 4 independent butterflies
      d[0] += __shfl_xor(d[0], off, 64);
      d[1] += __shfl_xor(d[1], off, 64);
      d[2] += __shfl_xor(d[2], off, 64);
      d[3] += __shfl_xor(d[3], off, 64);
    }
    #pragma unroll
    for (int u = 0; u < 4; ++u) {
      float sim = d[u] * INV_TEMP;
      maxneg = fmaxf(maxneg, sim);
      sumexp += __expf(sim);
    }
  }

  if (lane == 0) {
    float lse = logf(sumexp);
    wred[wave] = make_float2(lse - s0, (s0 >= maxneg) ? 1.0f : 0.0f);
  }
  __syncthreads();
  if (threadIdx.x == 0) {
    float l = 0.0f, a = 0.0f;
    #pragma unroll
    for (int w = 0; w < 4; ++w) { l += wred[w].x; a += wred[w].y; }
    partials[blockIdx.x] = make_float2(l, a);
  }
}

// Kernel 3: reduce 1024 block partials -> (loss, acc)
__global__ __launch_bounds__(256) void k_finalize(
    const float2* __restrict__ partials, float* __restrict__ out) {
  int t = threadIdx.x;
  float l = 0.0f, a = 0.0f;
  #pragma unroll
  for (int i = 0; i < 4; ++i) {
    float2 v = partials[t + 256 * i];
    l += v.x; a += v.y;
  }
  #pragma unroll
  for (int off = 1; off < 64; off <<= 1) {
    l += __shfl_xor(l, off, 64);
    a += __shfl_xor(a, off, 64);
  }
  __shared__ float2 wred[4];
  if ((t & 63) == 0) wred[t >> 6] = make_float2(l, a);
  __syncthreads();
  if (t == 0) {
    float ll = wred[0].x + wred[1].x + wred[2].x + wred[3].x;
    float aa = wred[0].y + wred[1].y + wred[2].y + wred[3].y;
    out[0] = ll * (1.0f / M_ROWS);
    out[1] = aa * (1.0f / M_ROWS);
  }
}

extern "C" void kernel_launch(void* const* d_in, const int* in_sizes, int n_in,
                              void* d_out, int out_size, void* d_ws, size_t ws_size,
                              hipStream_t stream) {
  const float* pred = (const float*)d_in[0];
  const float* enc  = (const float*)d_in[1];
  const int*   ids  = (const int*)d_in[2];
  float* out = (float*)d_out;

  // ws layout: nenc bf16 [4096*512] (4MB) | npred bf16 (4MB) | sim0[4096] | partials[1024] float2
  int4* nenc  = (int4*)d_ws;
  int4* npred = nenc + (size_t)M_ROWS * 64;
  float* sim0 = (float*)(npred + (size_t)M_ROWS * 64);
  float2* partials = (float2*)(sim0 + M_ROWS);

  k_gather_norm<<<M_ROWS / 4, 256, 0, stream>>>(pred, enc, ids, nenc, npred, sim0);
  k_contrast<<<M_ROWS / 4, 256, 0, stream>>>(nenc, npred, sim0, partials);
  k_finalize<<<1, 256, 0, stream>>>(partials, out);
}